// Round 6
// baseline (66.235 us; speedup 1.0000x reference)
//
#include <hip/hip_runtime.h>

// B=32768, D=1024, K=8, NS=10. Zero LDS, zero barriers, fully independent
// threads. Thread t (256/row) owns out[4t..4t+3]; it recomputes the 5
// (lo,hi) pairs c = 2t-3..2t+1 it needs directly from x (halo quads are
// L1-hits). Boundary tid<4 handled by a constant-index unrolled path.
#define D_LEN 1024
#define NS    10
#define LCC   516

__global__ __launch_bounds__(256) void wavecore_kernel(
    const float* __restrict__ x,
    const float* __restrict__ dec_lo, const float* __restrict__ dec_hi,
    const float* __restrict__ rec_lo, const float* __restrict__ rec_hi,
    const float* __restrict__ sp_c,   const int* __restrict__ sp_i,
    float* __restrict__ out)
{
    const int tid = threadIdx.x;
    const float* __restrict__ xr = x + (size_t)blockIdx.x * D_LEN;

    // Filters: uniform addresses, constant indices -> s_load / SGPRs.
    float fdl[8], fdh[8], frl[8], frh[8];
#pragma unroll
    for (int k = 0; k < 8; ++k) {
        fdl[k] = dec_lo[k]; fdh[k] = dec_hi[k];
        frl[k] = rec_lo[k]; frh[k] = rec_hi[k];
    }

    float res0 = 0.f, res1 = 0.f, res2 = 0.f, res3 = 0.f;
    float xo0 = 0.f, xo1 = 0.f, xo2 = 0.f, xo3 = 0.f;

    if (tid >= 4) {
        // ---- interior: window W = x[4t-13 .. 4t+2], own quad for residual ----
        const float  h  = xr[4 * tid - 13];
        const float4 qa = ((const float4*)xr)[tid - 3];
        const float4 qb = ((const float4*)xr)[tid - 2];
        const float4 qc = ((const float4*)xr)[tid - 1];
        const float4 qd = ((const float4*)xr)[tid];
        xo0 = qd.x; xo1 = qd.y; xo2 = qd.z; xo3 = qd.w;
        const float W[16] = { h,
                              qa.x, qa.y, qa.z, qa.w,
                              qb.x, qb.y, qb.z, qb.w,
                              qc.x, qc.y, qc.z, qc.w,
                              qd.x, qd.y, qd.z };
        // pairs P_i: c = 2t-3+i.  lo[c] = sum_j x[2c-j]*fdl[j] = sum_j W[7+2i-j]*fdl[j]
        float Plo[5], Phi[5];
#pragma unroll
        for (int i = 0; i < 5; ++i) {
            float aL = 0.f, aH = 0.f;
#pragma unroll
            for (int j = 0; j < 8; ++j) {
                const float v = W[7 + 2 * i - j];
                aL = fmaf(v, fdl[j], aL);
                aH = fmaf(v, fdh[j], aH);
            }
            Plo[i] = aL; Phi[i] = aH;
        }
        // sparse fold: rare, __any-guarded
#pragma unroll
        for (int n = 0; n < NS; ++n) {
            const int   s    = sp_i[n];
            const float v    = sp_c[n];
            const bool  isHi = (s >= LCC);
            const int   c    = isHi ? (s - LCC) : s;
            const bool  ok   = isHi || (s < 512);
            const int   d    = c - (2 * tid - 3);
            const bool  hit  = ok && (d >= 0) && (d < 5);
            if (__any(hit)) {
#pragma unroll
                for (int i = 0; i < 5; ++i) {
                    const float av = (hit && d == i) ? v : 0.f;
                    if (isHi) Phi[i] += av; else Plo[i] += av;   // isHi uniform
                }
            }
        }
        // recon: even t -> taps k=1,3,5,7 ; odd t -> k=0,2,4,6 (c ascends)
        res0 = Plo[0]*frl[1]+Phi[0]*frh[1] + Plo[1]*frl[3]+Phi[1]*frh[3]
             + Plo[2]*frl[5]+Phi[2]*frh[5] + Plo[3]*frl[7]+Phi[3]*frh[7];
        res1 = Plo[0]*frl[0]+Phi[0]*frh[0] + Plo[1]*frl[2]+Phi[1]*frh[2]
             + Plo[2]*frl[4]+Phi[2]*frh[4] + Plo[3]*frl[6]+Phi[3]*frh[6];
        res2 = Plo[1]*frl[1]+Phi[1]*frh[1] + Plo[2]*frl[3]+Phi[2]*frh[3]
             + Plo[3]*frl[5]+Phi[3]*frh[5] + Plo[4]*frl[7]+Phi[4]*frh[7];
        res3 = Plo[1]*frl[0]+Phi[1]*frh[0] + Plo[2]*frl[2]+Phi[2]*frh[2]
             + Plo[3]*frl[4]+Phi[3]*frh[4] + Plo[4]*frl[6]+Phi[4]*frh[6];
    } else {
        // ---- boundary: tid 0..3 (4 lanes of wave 0), all indices constant ----
        const float4 q0 = ((const float4*)xr)[0];
        const float4 q1 = ((const float4*)xr)[1];
        const float4 q2 = ((const float4*)xr)[2];
        const float4 q3 = ((const float4*)xr)[3];
        const float X[16] = { q0.x, q0.y, q0.z, q0.w,
                              q1.x, q1.y, q1.z, q1.w,
                              q2.x, q2.y, q2.z, q2.w,
                              q3.x, q3.y, q3.z, q3.w };
        // pairs c=0..7 with x-reflect: lo[c] = sum_j X[abs(2c-j)]*fdl[j]
        float Plo8[8], Phi8[8];
#pragma unroll
        for (int c = 0; c < 8; ++c) {
            float aL = 0.f, aH = 0.f;
#pragma unroll
            for (int j = 0; j < 8; ++j) {
                const int m  = 2 * c - j;
                const int mi = (m < 0) ? -m : m;
                const float v = X[mi];
                aL = fmaf(v, fdl[j], aL);
                aH = fmaf(v, fdh[j], aH);
            }
            Plo8[c] = aL; Phi8[c] = aH;
        }
        // sparse fold (uniform conditions -> scalar branches)
#pragma unroll
        for (int n = 0; n < NS; ++n) {
            const int   s    = sp_i[n];
            const float v    = sp_c[n];
            const bool  isHi = (s >= LCC);
            const int   c    = isHi ? (s - LCC) : s;
            const bool  ok   = isHi || (s < 512);
            if (ok && c < 8) {
#pragma unroll
                for (int cc = 0; cc < 8; ++cc)
                    if (c == cc) { if (isHi) Phi8[cc] += v; else Plo8[cc] += v; }
            }
        }
        // recon with pair-reflect: m = t+k-7, c = abs(m)/2 (all constexpr per T)
        float rtmp[4] = {0.f, 0.f, 0.f, 0.f};
#pragma unroll
        for (int T = 0; T < 4; ++T) {
            if (tid == T) {
#pragma unroll
                for (int j = 0; j < 4; ++j) {
                    const int t  = 4 * T + j;
                    const int k0 = (t & 1) ? 0 : 1;
                    float a = 0.f;
#pragma unroll
                    for (int u = 0; u < 4; ++u) {
                        const int k = k0 + 2 * u;
                        const int m = t + k - 7;
                        const int c = ((m < 0) ? -m : m) >> 1;
                        a = fmaf(Plo8[c], frl[k], a);
                        a = fmaf(Phi8[c], frh[k], a);
                    }
                    rtmp[j] = a;
                }
                xo0 = X[4*T]; xo1 = X[4*T+1]; xo2 = X[4*T+2]; xo3 = X[4*T+3];
            }
        }
        res0 = rtmp[0]; res1 = rtmp[1]; res2 = rtmp[2]; res3 = rtmp[3];
    }

    float4 r;
    r.x = res0 + xo0; r.y = res1 + xo1; r.z = res2 + xo2; r.w = res3 + xo3;
    ((float4*)(out + (size_t)blockIdx.x * D_LEN))[tid] = r;
}

extern "C" void kernel_launch(void* const* d_in, const int* in_sizes, int n_in,
                              void* d_out, int out_size, void* d_ws, size_t ws_size,
                              hipStream_t stream) {
    const float* x      = (const float*)d_in[0];
    const float* dec_lo = (const float*)d_in[1];
    const float* dec_hi = (const float*)d_in[2];
    const float* rec_lo = (const float*)d_in[3];
    const float* rec_hi = (const float*)d_in[4];
    const float* sp_c   = (const float*)d_in[5];
    const int*   sp_i   = (const int*)d_in[6];
    float* out = (float*)d_out;

    const int Brows = in_sizes[0] / D_LEN;   // 32768
    wavecore_kernel<<<Brows, 256, 0, stream>>>(x, dec_lo, dec_hi, rec_lo, rec_hi,
                                               sp_c, sp_i, out);
}

// Round 7
// 49.478 us; speedup vs baseline: 1.3387x; 1.3387x over previous
//
#include <hip/hip_runtime.h>

// B=32768, D=1024, K=8, NS=10.
// Kernel A: sparse correction is row-invariant + reconstruction is linear ->
//           precompute delta[1024] = rec(sparse-only pairs) once into d_ws.
// Kernel B: persistent blocks (GRID blocks, J rows each), software-pipelined:
//           prefetch row j+2 to regs, stage row j+1 to alt LDS buffer during
//           phase2 of row j. out = x + rec(x) + delta. No sparse in hot loop.
#define D_LEN 1024
#define K_LEN 8
#define NS    10
#define LCC   516
#define GRID  2048

// ---------------- Kernel A: delta = rec(sparse) ----------------
__global__ __launch_bounds__(256) void wave_delta(
    const float* __restrict__ rec_lo, const float* __restrict__ rec_hi,
    const float* __restrict__ sp_c,   const int* __restrict__ sp_i,
    float* __restrict__ delta)
{
    __shared__ __align__(16) float2 st[512];
    const int tid = threadIdx.x;

    float frl[K_LEN], frh[K_LEN];
#pragma unroll
    for (int k = 0; k < K_LEN; ++k) { frl[k] = rec_lo[k]; frh[k] = rec_hi[k]; }

    float4 z; z.x = 0.f; z.y = 0.f; z.z = 0.f; z.w = 0.f;
    ((float4*)st)[tid] = z;
    __syncthreads();
    if (tid < NS) {
        const int s = sp_i[tid];
        const float v = sp_c[tid];
        if (s < 512)       st[s].x = v;        // distinct indices -> no race
        else if (s >= LCC) st[s - LCC].y = v;  // lo c in [512,516) unused
    }
    __syncthreads();

    float res0, res1, res2, res3;
    if (tid >= 2) {
        const float4 qa = ((const float4*)st)[tid - 2];
        const float4 qb = ((const float4*)st)[tid - 1];
        const float4 qc = ((const float4*)st)[tid];
        const float p0l = qa.z, p0h = qa.w;
        const float p1l = qb.x, p1h = qb.y;
        const float p2l = qb.z, p2h = qb.w;
        const float p3l = qc.x, p3h = qc.y;
        const float p4l = qc.z, p4h = qc.w;
        res0 = p0l*frl[1] + p0h*frh[1] + p1l*frl[3] + p1h*frh[3]
             + p2l*frl[5] + p2h*frh[5] + p3l*frl[7] + p3h*frh[7];
        res1 = p0l*frl[0] + p0h*frh[0] + p1l*frl[2] + p1h*frh[2]
             + p2l*frl[4] + p2h*frh[4] + p3l*frl[6] + p3h*frh[6];
        res2 = p1l*frl[1] + p1h*frh[1] + p2l*frl[3] + p2h*frh[3]
             + p3l*frl[5] + p3h*frh[5] + p4l*frl[7] + p4h*frh[7];
        res3 = p1l*frl[0] + p1h*frh[0] + p2l*frl[2] + p2h*frh[2]
             + p3l*frl[4] + p3h*frh[4] + p4l*frl[6] + p4h*frh[6];
    } else {
        float acc[4];
#pragma unroll
        for (int j = 0; j < 4; ++j) {
            const int t  = 4 * tid + j;
            const int k0 = ((j & 1) ^ 1);
            float a = 0.f;
#pragma unroll
            for (int i = 0; i < 4; ++i) {
                const int k = k0 + 2 * i;
                int m = t + k - 7;
                m = (m < 0) ? -m : m;
                const float2 pv = st[m >> 1];
                a = fmaf(pv.x, frl[k], a);
                a = fmaf(pv.y, frh[k], a);
            }
            acc[j] = a;
        }
        res0 = acc[0]; res1 = acc[1]; res2 = acc[2]; res3 = acc[3];
    }
    float4 r; r.x = res0; r.y = res1; r.z = res2; r.w = res3;
    ((float4*)delta)[tid] = r;
}

// ---------------- Kernel B: pipelined main ----------------
__global__ __launch_bounds__(256) void wavecore_kernel(
    const float* __restrict__ x,
    const float* __restrict__ dec_lo, const float* __restrict__ dec_hi,
    const float* __restrict__ rec_lo, const float* __restrict__ rec_hi,
    const float* __restrict__ delta,
    float* __restrict__ out, int J)
{
    __shared__ __align__(16) float  sx[2][D_LEN];
    __shared__ __align__(16) float2 st[512];

    const int tid = threadIdx.x;

    float fdl[K_LEN], fdh[K_LEN], frl[K_LEN], frh[K_LEN];
#pragma unroll
    for (int k = 0; k < K_LEN; ++k) {
        fdl[k] = dec_lo[k]; fdh[k] = dec_hi[k];
        frl[k] = rec_lo[k]; frh[k] = rec_hi[k];
    }
    const float4 dq = ((const float4*)delta)[tid];

    // prologue: row0 -> regs+LDS[0]; prefetch row1 -> xn
    size_t off = (size_t)blockIdx.x * D_LEN + 4 * (size_t)tid;
    const size_t rstride = (size_t)GRID * D_LEN;
    float4 xv = *(const float4*)(x + off);
    ((float4*)sx[0])[tid] = xv;
    float4 xn;
    { xn = *(const float4*)(x + off + rstride); }          // J>=2 always here
    __syncthreads();                                       // sx[0] ready

    int cur = 0;
#pragma unroll 1
    for (int j = 0; j < J; ++j) {
        // early-issue prefetch of row j+2
        float4 xn2;
        if (j + 2 < J) xn2 = *(const float4*)(x + off + 2 * rstride);

        // ---- phase 2 on sx[cur] + own regs ----
        const float* sxc = sx[cur];
        float lo0 = 0.f, hi0 = 0.f, lo1 = 0.f, hi1 = 0.f;
        if (tid >= 2) {
            const float4 wa = ((const float4*)sxc)[tid - 2];
            const float4 wb = ((const float4*)sxc)[tid - 1];
            const float w[12] = { wa.x, wa.y, wa.z, wa.w,
                                  wb.x, wb.y, wb.z, wb.w,
                                  xv.x, xv.y, xv.z, xv.w };
#pragma unroll
            for (int jj = 0; jj < K_LEN; ++jj) {
                const float v0 = w[8  - jj];
                const float v1 = w[10 - jj];
                lo0 = fmaf(v0, fdl[jj], lo0);
                hi0 = fmaf(v0, fdh[jj], hi0);
                lo1 = fmaf(v1, fdl[jj], lo1);
                hi1 = fmaf(v1, fdh[jj], hi1);
            }
        } else {
#pragma unroll
            for (int q = 0; q < 2; ++q) {
                const int c = 2 * tid + q;
                float aL = 0.f, aH = 0.f;
#pragma unroll
                for (int jj = 0; jj < K_LEN; ++jj) {
                    int m = 2 * c - jj;
                    m = (m < 0) ? -m : m;
                    const float v = sxc[m];
                    aL = fmaf(v, fdl[jj], aL);
                    aH = fmaf(v, fdh[jj], aH);
                }
                if (q == 0) { lo0 = aL; hi0 = aH; }
                else        { lo1 = aL; hi1 = aH; }
            }
        }
        {
            float4 pr; pr.x = lo0; pr.y = hi0; pr.z = lo1; pr.w = hi1;
            ((float4*)st)[tid] = pr;
        }
        // stage row j+1 into the other buffer (no reader conflict)
        if (j + 1 < J) ((float4*)sx[cur ^ 1])[tid] = xn;
        __syncthreads();                                   // st + sx[nxt] ready

        // ---- phase 3 + store ----
        float res0, res1, res2, res3;
        if (tid >= 2) {
            const float4 qa = ((const float4*)st)[tid - 2];
            const float4 qb = ((const float4*)st)[tid - 1];
            const float p0l = qa.z, p0h = qa.w;
            const float p1l = qb.x, p1h = qb.y;
            const float p2l = qb.z, p2h = qb.w;
            const float p3l = lo0,  p3h = hi0;
            const float p4l = lo1,  p4h = hi1;
            res0 = p0l*frl[1] + p0h*frh[1] + p1l*frl[3] + p1h*frh[3]
                 + p2l*frl[5] + p2h*frh[5] + p3l*frl[7] + p3h*frh[7];
            res1 = p0l*frl[0] + p0h*frh[0] + p1l*frl[2] + p1h*frh[2]
                 + p2l*frl[4] + p2h*frh[4] + p3l*frl[6] + p3h*frh[6];
            res2 = p1l*frl[1] + p1h*frh[1] + p2l*frl[3] + p2h*frh[3]
                 + p3l*frl[5] + p3h*frh[5] + p4l*frl[7] + p4h*frh[7];
            res3 = p1l*frl[0] + p1h*frh[0] + p2l*frl[2] + p2h*frh[2]
                 + p3l*frl[4] + p3h*frh[4] + p4l*frl[6] + p4h*frh[6];
        } else {
            float acc[4];
#pragma unroll
            for (int jj = 0; jj < 4; ++jj) {
                const int t  = 4 * tid + jj;
                const int k0 = ((jj & 1) ^ 1);
                float a = 0.f;
#pragma unroll
                for (int i = 0; i < 4; ++i) {
                    const int k = k0 + 2 * i;
                    int m = t + k - 7;
                    m = (m < 0) ? -m : m;
                    const float2 pv = st[m >> 1];
                    a = fmaf(pv.x, frl[k], a);
                    a = fmaf(pv.y, frh[k], a);
                }
                acc[jj] = a;
            }
            res0 = acc[0]; res1 = acc[1]; res2 = acc[2]; res3 = acc[3];
        }

        float4 r;
        r.x = res0 + xv.x + dq.x;
        r.y = res1 + xv.y + dq.y;
        r.z = res2 + xv.z + dq.z;
        r.w = res3 + xv.w + dq.w;
        *(float4*)(out + off) = r;
        __syncthreads();                                   // st/sx[cur] reusable

        xv = xn; xn = xn2; cur ^= 1; off += rstride;
    }
}

extern "C" void kernel_launch(void* const* d_in, const int* in_sizes, int n_in,
                              void* d_out, int out_size, void* d_ws, size_t ws_size,
                              hipStream_t stream) {
    const float* x      = (const float*)d_in[0];
    const float* dec_lo = (const float*)d_in[1];
    const float* dec_hi = (const float*)d_in[2];
    const float* rec_lo = (const float*)d_in[3];
    const float* rec_hi = (const float*)d_in[4];
    const float* sp_c   = (const float*)d_in[5];
    const int*   sp_i   = (const int*)d_in[6];
    float* out   = (float*)d_out;
    float* delta = (float*)d_ws;   // 4 KB

    const int Brows = in_sizes[0] / D_LEN;   // 32768
    const int J     = Brows / GRID;          // 16

    wave_delta<<<1, 256, 0, stream>>>(rec_lo, rec_hi, sp_c, sp_i, delta);
    wavecore_kernel<<<GRID, 256, 0, stream>>>(x, dec_lo, dec_hi, rec_lo, rec_hi,
                                              delta, out, J);
}

// Round 8
// 46.622 us; speedup vs baseline: 1.4207x; 1.0613x over previous
//
#include <hip/hip_runtime.h>

// B=32768, D=1024, K=8, NS=10.
// Single persistent kernel, GRID blocks x J rows. Per block:
//  - inline delta: sparse correction is row-invariant and recon is linear ->
//    compute correction quad dq once per block (st[0] scratch, 3 barriers).
//  - main loop: ONE barrier per row. Double-buffered sx (x rows) AND st
//    (pair quads). Region (A_j, A_{j+1}) holds {phase3_j: read st[s];
//    store_j; phase2_{j+1}: read sx[c^1], write st[s^1]; stage_{j+1}:
//    write sx[c]} -- all cross-wave hazards are buffer-disjoint.
//  - prefetch depth 2 (regs), out = x + rec(x) + dq.
#define D_LEN 1024
#define K_LEN 8
#define NS    10
#define LCC   516
#define GRID  2048

__global__ __launch_bounds__(256) void wavecore_kernel(
    const float* __restrict__ x,
    const float* __restrict__ dec_lo, const float* __restrict__ dec_hi,
    const float* __restrict__ rec_lo, const float* __restrict__ rec_hi,
    const float* __restrict__ sp_c,   const int* __restrict__ sp_i,
    float* __restrict__ out, int J)
{
    __shared__ __align__(16) float  sx[2][D_LEN];
    __shared__ __align__(16) float2 st[2][512];

    const int tid = threadIdx.x;

    float fdl[K_LEN], fdh[K_LEN], frl[K_LEN], frh[K_LEN];
#pragma unroll
    for (int k = 0; k < K_LEN; ++k) {
        fdl[k] = dec_lo[k]; fdh[k] = dec_hi[k];
        frl[k] = rec_lo[k]; frh[k] = rec_hi[k];
    }

    // ---- inline delta: dq = rec(sparse-only pairs) for this thread's quad ----
    float dq0, dq1, dq2, dq3;
    {
        float4 z; z.x = 0.f; z.y = 0.f; z.z = 0.f; z.w = 0.f;
        ((float4*)st[0])[tid] = z;
        __syncthreads();
        if (tid < NS) {
            const int   s = sp_i[tid];
            const float v = sp_c[tid];
            if (s < 512)       st[0][s].x = v;        // distinct indices, no race
            else if (s >= LCC) st[0][s - LCC].y = v;  // lo c in [512,516) unused
        }
        __syncthreads();
        if (tid >= 2) {
            const float4 qa = ((const float4*)st[0])[tid - 2];
            const float4 qb = ((const float4*)st[0])[tid - 1];
            const float4 qc = ((const float4*)st[0])[tid];
            const float p0l = qa.z, p0h = qa.w;
            const float p1l = qb.x, p1h = qb.y;
            const float p2l = qb.z, p2h = qb.w;
            const float p3l = qc.x, p3h = qc.y;
            const float p4l = qc.z, p4h = qc.w;
            dq0 = p0l*frl[1] + p0h*frh[1] + p1l*frl[3] + p1h*frh[3]
                + p2l*frl[5] + p2h*frh[5] + p3l*frl[7] + p3h*frh[7];
            dq1 = p0l*frl[0] + p0h*frh[0] + p1l*frl[2] + p1h*frh[2]
                + p2l*frl[4] + p2h*frh[4] + p3l*frl[6] + p3h*frh[6];
            dq2 = p1l*frl[1] + p1h*frh[1] + p2l*frl[3] + p2h*frh[3]
                + p3l*frl[5] + p3h*frh[5] + p4l*frl[7] + p4h*frh[7];
            dq3 = p1l*frl[0] + p1h*frh[0] + p2l*frl[2] + p2h*frh[2]
                + p3l*frl[4] + p3h*frh[4] + p4l*frl[6] + p4h*frh[6];
        } else {
            float acc[4];
#pragma unroll
            for (int j = 0; j < 4; ++j) {
                const int t  = 4 * tid + j;
                const int k0 = ((j & 1) ^ 1);
                float a = 0.f;
#pragma unroll
                for (int i = 0; i < 4; ++i) {
                    const int k = k0 + 2 * i;
                    int m = t + k - 7;
                    m = (m < 0) ? -m : m;
                    const float2 pv = st[0][m >> 1];
                    a = fmaf(pv.x, frl[k], a);
                    a = fmaf(pv.y, frh[k], a);
                }
                acc[j] = a;
            }
            dq0 = acc[0]; dq1 = acc[1]; dq2 = acc[2]; dq3 = acc[3];
        }
        __syncthreads();   // st[0] free for reuse
    }

    // ---- prologue: row0 -> regs+sx[0]; row1 -> xn ----
    size_t off = (size_t)blockIdx.x * D_LEN + 4 * (size_t)tid;
    const size_t rstride = (size_t)GRID * D_LEN;
    float4 xv = *(const float4*)(x + off);
    ((float4*)sx[0])[tid] = xv;
    float4 xn = *(const float4*)(x + off + rstride);   // J >= 2
    __syncthreads();                                   // sx[0] ready

    int cur = 0, sb = 0;
#pragma unroll 1
    for (int j = 0; j < J; ++j) {
        // prefetch row j+2 (uniform guard)
        float4 xn2;
        if (j + 2 < J) xn2 = *(const float4*)(x + off + 2 * rstride);

        // ---- phase 2 on sx[cur] + own regs -> st[sb] ----
        const float* sxc = sx[cur];
        float lo0 = 0.f, hi0 = 0.f, lo1 = 0.f, hi1 = 0.f;
        if (tid >= 2) {
            const float4 wa = ((const float4*)sxc)[tid - 2];
            const float4 wb = ((const float4*)sxc)[tid - 1];
            const float w[12] = { wa.x, wa.y, wa.z, wa.w,
                                  wb.x, wb.y, wb.z, wb.w,
                                  xv.x, xv.y, xv.z, xv.w };
#pragma unroll
            for (int jj = 0; jj < K_LEN; ++jj) {
                const float v0 = w[8  - jj];
                const float v1 = w[10 - jj];
                lo0 = fmaf(v0, fdl[jj], lo0);
                hi0 = fmaf(v0, fdh[jj], hi0);
                lo1 = fmaf(v1, fdl[jj], lo1);
                hi1 = fmaf(v1, fdh[jj], hi1);
            }
        } else {
#pragma unroll
            for (int q = 0; q < 2; ++q) {
                const int c = 2 * tid + q;
                float aL = 0.f, aH = 0.f;
#pragma unroll
                for (int jj = 0; jj < K_LEN; ++jj) {
                    int m = 2 * c - jj;
                    m = (m < 0) ? -m : m;
                    const float v = sxc[m];
                    aL = fmaf(v, fdl[jj], aL);
                    aH = fmaf(v, fdh[jj], aH);
                }
                if (q == 0) { lo0 = aL; hi0 = aH; }
                else        { lo1 = aL; hi1 = aH; }
            }
        }
        {
            float4 pr; pr.x = lo0; pr.y = hi0; pr.z = lo1; pr.w = hi1;
            ((float4*)st[sb])[tid] = pr;
        }
        // stage row j+1 into alternate x-buffer
        if (j + 1 < J) ((float4*)sx[cur ^ 1])[tid] = xn;
        __syncthreads();   // the ONE barrier: st[sb] + sx[cur^1] ready

        // ---- phase 3 from st[sb] + own pair regs; store ----
        float res0, res1, res2, res3;
        if (tid >= 2) {
            const float4 qa = ((const float4*)st[sb])[tid - 2];
            const float4 qb = ((const float4*)st[sb])[tid - 1];
            const float p0l = qa.z, p0h = qa.w;
            const float p1l = qb.x, p1h = qb.y;
            const float p2l = qb.z, p2h = qb.w;
            const float p3l = lo0,  p3h = hi0;
            const float p4l = lo1,  p4h = hi1;
            res0 = p0l*frl[1] + p0h*frh[1] + p1l*frl[3] + p1h*frh[3]
                 + p2l*frl[5] + p2h*frh[5] + p3l*frl[7] + p3h*frh[7];
            res1 = p0l*frl[0] + p0h*frh[0] + p1l*frl[2] + p1h*frh[2]
                 + p2l*frl[4] + p2h*frh[4] + p3l*frl[6] + p3h*frh[6];
            res2 = p1l*frl[1] + p1h*frh[1] + p2l*frl[3] + p2h*frh[3]
                 + p3l*frl[5] + p3h*frh[5] + p4l*frl[7] + p4h*frh[7];
            res3 = p1l*frl[0] + p1h*frh[0] + p2l*frl[2] + p2h*frh[2]
                 + p3l*frl[4] + p3h*frh[4] + p4l*frl[6] + p4h*frh[6];
        } else {
            float acc[4];
#pragma unroll
            for (int jj = 0; jj < 4; ++jj) {
                const int t  = 4 * tid + jj;
                const int k0 = ((jj & 1) ^ 1);
                float a = 0.f;
#pragma unroll
                for (int i = 0; i < 4; ++i) {
                    const int k = k0 + 2 * i;
                    int m = t + k - 7;
                    m = (m < 0) ? -m : m;
                    const float2 pv = st[sb][m >> 1];
                    a = fmaf(pv.x, frl[k], a);
                    a = fmaf(pv.y, frh[k], a);
                }
                acc[jj] = a;
            }
            res0 = acc[0]; res1 = acc[1]; res2 = acc[2]; res3 = acc[3];
        }

        float4 r;
        r.x = res0 + xv.x + dq0;
        r.y = res1 + xv.y + dq1;
        r.z = res2 + xv.z + dq2;
        r.w = res3 + xv.w + dq3;
        *(float4*)(out + off) = r;

        xv = xn; xn = xn2; cur ^= 1; sb ^= 1; off += rstride;
    }
}

extern "C" void kernel_launch(void* const* d_in, const int* in_sizes, int n_in,
                              void* d_out, int out_size, void* d_ws, size_t ws_size,
                              hipStream_t stream) {
    const float* x      = (const float*)d_in[0];
    const float* dec_lo = (const float*)d_in[1];
    const float* dec_hi = (const float*)d_in[2];
    const float* rec_lo = (const float*)d_in[3];
    const float* rec_hi = (const float*)d_in[4];
    const float* sp_c   = (const float*)d_in[5];
    const int*   sp_i   = (const int*)d_in[6];
    float* out = (float*)d_out;

    const int Brows = in_sizes[0] / D_LEN;   // 32768
    const int J     = Brows / GRID;          // 16

    wavecore_kernel<<<GRID, 256, 0, stream>>>(x, dec_lo, dec_hi, rec_lo, rec_hi,
                                              sp_c, sp_i, out, J);
}